// Round 23
// baseline (138.332 us; speedup 1.0000x reference)
//
#include <hip/hip_runtime.h>
#include <hip/hip_bf16.h>
#include <cstdint>
#include <cstddef>

#define BATCH 32
#define NPTS  2048
#define NFLAT (BATCH * NPTS)   // 65536
#define MROWS 32               // rows per block in k_mask (8 per wave)

typedef __attribute__((ext_vector_type(8))) short bf16x8;    // 8 bf16 (4 VGPRs)
typedef __attribute__((ext_vector_type(4))) short bf16x4;    // 4 bf16 (2 VGPRs)
typedef __attribute__((ext_vector_type(4))) float f32x4;     // 16x16 C/D frag
typedef __attribute__((ext_vector_type(16))) float f32x16;   // 32x32 C/D frag

__device__ inline unsigned short f2b(float v) {
    __hip_bfloat16 h = __float2bfloat16(v);
    return __builtin_bit_cast(unsigned short, h);
}

__device__ inline void gl_lds16(const void* g, void* l) {
    __builtin_amdgcn_global_load_lds(
        (const __attribute__((address_space(1))) unsigned int*)g,
        (__attribute__((address_space(3))) unsigned int*)l, 16, 0, 0);
}

// ---------------- ws layout (bytes) ----------------
// dinv  : f32  [65536]            @ 0
// maskT : u32  [b][64][2048]      @ 262144    (16 MB)  TRANSPOSED: word-plane major
// G1    : bf16 fragnat(64)        @ 17039360  (8 MB)   dinv*h1, B-frag layout
// G2    : bf16 fragnat(128)       @ 50593792  (16 MB)  dinv*h2, B-frag layout
// Wp    : bf16 fragnat W2|W3      @ 67371008  (80 KB)
#define OFF_DINV 0
#define OFF_MASK 262144
#define OFF_G1   17039360
#define OFF_G2   50593792
#define OFF_WB   67371008

// ---------------- pack W2/W3 to bf16 fragment-native B-operand layout ----------------
__global__ __launch_bounds__(256) void k_cvtW2(const float* __restrict__ W2,
                                               const float* __restrict__ W3,
                                               unsigned short* __restrict__ Wp2,
                                               unsigned short* __restrict__ Wp3) {
    int i = blockIdx.x * 256 + threadIdx.x;   // grid 128 blocks -> i < 32768
    if (i < 64 * 128) {
        int k = i >> 7, c = i & 127;
        size_t off = (((size_t)(k >> 4) * 4 + (c >> 5)) * 64
                      + ((((k >> 3) & 1) << 5) | (c & 31))) * 8 + (k & 7);
        Wp2[off] = f2b(W2[i]);
    }
    {
        int k = i >> 8, c = i & 255;
        size_t off = (((size_t)(k >> 4) * 8 + (c >> 5)) * 64
                      + ((((k >> 3) & 1) << 5) | (c & 31))) * 8 + (k & 7);
        Wp3[off] = f2b(W3[i]);
    }
}

// ---------------- adjacency bitmask (transposed layout) + dinv ----------------
__global__ __launch_bounds__(256) void k_mask(const float* __restrict__ pts,
                                              float* __restrict__ dinv,
                                              uint32_t* __restrict__ maskT) {
    const int b = blockIdx.y;
    const int row0 = blockIdx.x * MROWS;
    const int tid = threadIdx.x, lane = tid & 63, wv = tid >> 6;
    __shared__ float px[2112], py[2112];
    __shared__ uint32_t tb[64][MROWS + 1];
    const float2* P = (const float2*)(pts + (size_t)b * NPTS * 2);
    for (int j = tid; j < NPTS; j += 256) {
        float2 p = P[j];
        px[j + (j >> 5)] = p.x; py[j + (j >> 5)] = p.y;
    }
    __syncthreads();
    const int base = 33 * lane;
    for (int rr = 0; rr < MROWS / 4; ++rr) {
        const int il = wv * (MROWS / 4) + rr;
        const int i = row0 + il;
        const float xi = px[i + (i >> 5)], yi = py[i + (i >> 5)];
        uint32_t bits = 0;
        #pragma unroll
        for (int t = 0; t < 32; ++t) {
            float dx = xi - px[base + t], dy = yi - py[base + t];
            bits |= (dx * dx + dy * dy < 1.0f) ? (1u << t) : 0u;
        }
        tb[lane][il] = bits;
        int cnt = __popc(bits);
        #pragma unroll
        for (int off = 32; off; off >>= 1) cnt += __shfl_xor(cnt, off);
        if (lane == 0) dinv[b * NPTS + i] = rsqrtf((float)(cnt + 1));
    }
    __syncthreads();
    const int w = tid >> 2, il0 = (tid & 3) * 8;
    uint32_t* dst = maskT + ((size_t)b * 64 + w) * NPTS + row0 + il0;
    #pragma unroll
    for (int e = 0; e < 8; ++e) dst[e] = tb[w][il0 + e];
}

// ---------------- layer 1 masked MFMA -> G1 = dinv*h1, fragment-native(64) ----------
__global__ __launch_bounds__(256) void k_l1m(const float* __restrict__ pts,
                                             const float* __restrict__ W1,
                                             const float* __restrict__ b1,
                                             const float* __restrict__ dinv,
                                             const uint32_t* __restrict__ maskT,
                                             unsigned short* __restrict__ G1) {
    const int lid = blockIdx.x;
    const int g = (lid & 7) * 64 + (lid >> 3);   // bijective XCD swizzle
    const int b = g >> 4;
    const int row0 = (g & 15) * 128;
    const int tid = threadIdx.x;
    const int lane = tid & 63, wv = tid >> 6;
    const int l15 = lane & 15, lg = lane >> 4;

    __shared__ uint32_t Ms[64][128];
    __shared__ unsigned short Ubf[NPTS], Vbf[NPTS];
    __shared__ alignas(128) unsigned short LUT4[64];
    __shared__ float sdinv[128];

    if (tid < 16) {
        ushort4 e;
        e.x = (tid & 1) ? 0x3F80 : 0; e.y = (tid & 2) ? 0x3F80 : 0;
        e.z = (tid & 4) ? 0x3F80 : 0; e.w = (tid & 8) ? 0x3F80 : 0;
        *(ushort4*)&LUT4[tid * 4] = e;
    }
    if (tid < 128) sdinv[tid] = dinv[b * NPTS + row0 + tid];
    {
        const float2* P = (const float2*)(pts + (size_t)b * NPTS * 2);
        const float* dvp = dinv + (size_t)b * NPTS;
        const int j0 = tid * 8;
        #pragma unroll
        for (int e = 0; e < 8; ++e) {
            float d = dvp[j0 + e]; float2 p = P[j0 + e];
            Ubf[j0 + e] = f2b(d * p.x); Vbf[j0 + e] = f2b(d * p.y);
        }
    }
    {
        const uint32_t* msrc = maskT + (size_t)b * 64 * NPTS + row0;
        #pragma unroll
        for (int k = 0; k < 8; ++k) {
            int idx = tid + k * 256;
            int w = idx >> 5, c4 = idx & 31;
            *(uint4*)&Ms[w][c4 * 4] = *(const uint4*)(msrc + (size_t)w * NPTS + c4 * 4);
        }
    }
    __syncthreads();

    f32x4 acc0 = (f32x4){0.f, 0.f, 0.f, 0.f};
    f32x4 acc1 = (f32x4){0.f, 0.f, 0.f, 0.f};
    const int lrow = wv * 32 + l15;
    const bf16x8 zb = (bf16x8){0, 0, 0, 0, 0, 0, 0, 0};

    for (int kt = 0; kt < 64; ++kt) {
        bf16x8 ub = *(const bf16x8*)&Ubf[kt * 32 + lg * 8];
        bf16x8 vb = *(const bf16x8*)&Vbf[kt * 32 + lg * 8];
        bf16x8 bf = (l15 == 0) ? ub : ((l15 == 1) ? vb : zb);
        #pragma unroll
        for (int mf = 0; mf < 2; ++mf) {
            const int row = row0 + lrow + mf * 16;
            uint32_t mw = Ms[kt][lrow + mf * 16];
            uint32_t by = (mw >> (lg * 8)) & 0xffu;
            bf16x4 lo = *(const bf16x4*)&LUT4[(by & 15u) * 4];
            bf16x4 hi = *(const bf16x4*)&LUT4[(by >> 4) * 4];
            bf16x8 af = __builtin_shufflevector(lo, hi, 0, 1, 2, 3, 4, 5, 6, 7);
            if (kt == (row >> 5)) {
                int e = (row & 31) - lg * 8;
                #pragma unroll
                for (int e2 = 0; e2 < 8; ++e2)
                    if (e2 == e) af[e2] = (short)0x4000;
            }
            if (mf == 0) acc0 = __builtin_amdgcn_mfma_f32_16x16x32_bf16(af, bf, acc0, 0, 0, 0);
            else         acc1 = __builtin_amdgcn_mfma_f32_16x16x32_bf16(af, bf, acc1, 0, 0, 0);
        }
    }

    float w1x[4], w1y[4], bb4[4];
    #pragma unroll
    for (int g4 = 0; g4 < 4; ++g4) {
        w1x[g4] = W1[l15 + 16 * g4];
        w1y[g4] = W1[64 + l15 + 16 * g4];
        bb4[g4] = b1[l15 + 16 * g4];
    }
    #pragma unroll
    for (int mf = 0; mf < 2; ++mf) {
        const int ks1 = mf | ((wv & 1) << 1);
        const int kt1 = (row0 >> 6) + (wv >> 1);
        #pragma unroll
        for (int r = 0; r < 4; ++r) {
            float av = (mf == 0) ? acc0[r] : acc1[r];
            float sx = __shfl(av, (lane & 48));
            float sy = __shfl(av, (lane & 48) | 1);
            const int rloc = wv * 32 + mf * 16 + lg * 4 + r;
            const float di = sdinv[rloc];
            const int e1 = (lg * 4 + r) & 7;
            const int kh1 = lg >> 1;
            #pragma unroll
            for (int g4 = 0; g4 < 4; ++g4) {
                float h = fmaxf(di * (sx * w1x[g4] + sy * w1y[g4]) + bb4[g4], 0.f);
                size_t off = ((((size_t)(b * 32 + kt1) * 2 + (g4 >> 1)) * 4 + ks1) * 512)
                             + (size_t)((kh1 << 5) | (l15 + 16 * (g4 & 1))) * 8 + e1;
                G1[off] = f2b(di * h);
            }
        }
    }
}

// ---------------- fused masked GCN layer, counted-vmcnt pipeline, regs-masks ----------
// Z=(A+I)@G (CIN cols): double-buffered fragment-native staging + double-buffered
// mask REGISTERS (no Ms LDS -> 34KB LDS -> up to 4 blocks/CU). Per tile vmem =
// stage(CIN/32) + 4 mask loads, all counted; steady-state vmcnt never 0.
// Epilogue: Z -> bf16 LDS (unions Ys dbuf), small GEMM vs fragnat W, write out/G.
template<int CIN, int COUT, bool RELU, bool F32OUT>
__global__ __launch_bounds__(256, 2) void k_gcnF(const uint32_t* __restrict__ maskT,
                                                 const float* __restrict__ dinv,
                                                 const unsigned short* __restrict__ G,
                                                 const unsigned short* __restrict__ Wp,
                                                 const float* __restrict__ bias,
                                                 void* __restrict__ outp) {
    constexpr int BM = 128;
    constexpr int NF = CIN / 64;          // 32-col B-frags per wave (2x2 wave grid)
    constexpr int LSZ = (2 * CIN * 64 > 128 * (CIN + 4)) ? 2 * CIN * 64 : 128 * (CIN + 4);
    const int lid = blockIdx.x;
    const int g = (lid & 7) * 64 + (lid >> 3);   // bijective XCD swizzle
    const int b = g >> 4;
    const int row0 = (g & 15) * BM;
    const int tid = threadIdx.x;
    const int lane = tid & 63, wv = tid >> 6;
    const int wm = wv >> 1, wn = wv & 1;
    const int l31 = lane & 31, lg2 = lane >> 5;

    __shared__ alignas(16) unsigned short YsZ[LSZ];   // Ys dbuf (main) / Zs (epilogue)
    __shared__ alignas(128) unsigned short LUT4[64];
    __shared__ float sdinv[BM];

    if (tid < 16) {
        ushort4 e;
        e.x = (tid & 1) ? 0x3F80 : 0; e.y = (tid & 2) ? 0x3F80 : 0;
        e.z = (tid & 4) ? 0x3F80 : 0; e.w = (tid & 8) ? 0x3F80 : 0;
        *(ushort4*)&LUT4[tid * 4] = e;
    }
    if (tid < BM) sdinv[tid] = dinv[b * NPTS + row0 + tid];

    f32x16 acc[2][NF];
    #pragma unroll
    for (int mf = 0; mf < 2; ++mf)
        #pragma unroll
        for (int nf = 0; nf < NF; ++nf)
            #pragma unroll
            for (int r = 0; r < 16; ++r)
                acc[mf][nf][r] = 0.f;

    const int ktd = (row0 >> 6) + wm;
    const int arow = wm * 64 + l31;
    // per-lane mask base: plane stride NPTS; 32 lanes read 128B contiguous per load
    const uint32_t* mtb = maskT + (size_t)b * 64 * NPTS + row0 + arow;

    auto stage = [&](int buf, int kt) {
        const unsigned short* ysrc = G + (size_t)(b * 32 + kt) * (CIN / 32) * 2048;
        #pragma unroll
        for (int q = 0; q < CIN / 32; ++q) {
            int fi = wv * (CIN / 32) + q;
            gl_lds16(ysrc + (size_t)fi * 512 + lane * 8,
                     (char*)YsZ + buf * (CIN * 128) + fi * 1024);
        }
    };
    auto mload = [&](uint32_t (&M)[2][2], int kt) {
        #pragma unroll
        for (int mf = 0; mf < 2; ++mf)
            #pragma unroll
            for (int q = 0; q < 2; ++q)
                M[mf][q] = mtb[(size_t)(kt * 2 + q) * NPTS + mf * 32];
    };
    auto body = [&](int buf, int kt, const uint32_t (&M)[2][2]) {
        const char* ybase = (const char*)YsZ + buf * (CIN * 128);
        #pragma unroll
        for (int ks = 0; ks < 4; ++ks) {
            bf16x8 af[2];
            #pragma unroll
            for (int mf = 0; mf < 2; ++mf) {
                uint32_t by = (M[mf][ks >> 1] >> (((ks & 1) * 2 + lg2) * 8)) & 0xffu;
                bf16x4 lo = *(const bf16x4*)&LUT4[(by & 15u) * 4];
                bf16x4 hi = *(const bf16x4*)&LUT4[(by >> 4) * 4];
                af[mf] = __builtin_shufflevector(lo, hi, 0, 1, 2, 3, 4, 5, 6, 7);
            }
            if (kt == ktd) {
                #pragma unroll
                for (int mf = 0; mf < 2; ++mf) {
                    int e = mf * 32 + l31 - ks * 16 - lg2 * 8;
                    #pragma unroll
                    for (int e2 = 0; e2 < 8; ++e2)
                        if (e2 == e) af[mf][e2] = (short)0x4000;
                }
            }
            #pragma unroll
            for (int nf = 0; nf < NF; ++nf) {
                bf16x8 bf = *(const bf16x8*)(ybase
                            + ((((wn * NF + nf) * 4 + ks) * 64 + lane) << 4));
                #pragma unroll
                for (int mf = 0; mf < 2; ++mf)
                    acc[mf][nf] = __builtin_amdgcn_mfma_f32_32x32x16_bf16(af[mf], bf, acc[mf][nf], 0, 0, 0);
            }
        }
    };

    uint32_t MA[2][2], MB[2][2];
    __syncthreads();            // publish LUT/sdinv; vmem queue empty
    stage(0, 0); mload(MA, 0);
    for (int kt = 0; kt < 32; kt += 2) {
        mload(MB, kt + 1); stage(1, kt + 1);
        if constexpr (CIN == 128) asm volatile("s_waitcnt vmcnt(8)" ::: "memory");
        else                      asm volatile("s_waitcnt vmcnt(6)" ::: "memory");
        __builtin_amdgcn_s_barrier();
        body(0, kt, MA);
        __builtin_amdgcn_s_barrier();
        if (kt + 2 < 32) {
            mload(MA, kt + 2); stage(0, kt + 2);
            if constexpr (CIN == 128) asm volatile("s_waitcnt vmcnt(8)" ::: "memory");
            else                      asm volatile("s_waitcnt vmcnt(6)" ::: "memory");
        } else {
            asm volatile("s_waitcnt vmcnt(0)" ::: "memory");
        }
        __builtin_amdgcn_s_barrier();
        body(1, kt + 1, MB);
        __builtin_amdgcn_s_barrier();
    }

    // ---- epilogue stage 1: Z -> bf16 LDS [128][CIN+4] (aliases Ys dbuf; drained) ----
    #pragma unroll
    for (int mf = 0; mf < 2; ++mf)
        #pragma unroll
        for (int nf = 0; nf < NF; ++nf) {
            const int col = wn * (CIN / 2) + nf * 32 + l31;
            #pragma unroll
            for (int reg = 0; reg < 16; ++reg) {
                const int row = wm * 64 + mf * 32 + (reg & 3) + 8 * (reg >> 2) + 4 * lg2;
                YsZ[row * (CIN + 4) + col] = f2b(acc[mf][nf][reg]);
            }
        }
    __syncthreads();

    // ---- epilogue stage 2: Z @ W (+bias), W fragment-native from global (L2-hot) ----
    f32x16 acc2[2][COUT / 64];
    #pragma unroll
    for (int amf = 0; amf < 2; ++amf)
        #pragma unroll
        for (int cnf = 0; cnf < COUT / 64; ++cnf)
            #pragma unroll
            for (int r = 0; r < 16; ++r)
                acc2[amf][cnf][r] = 0.f;

    #pragma unroll
    for (int kq = 0; kq < CIN / 16; ++kq) {
        bf16x8 za[2];
        #pragma unroll
        for (int amf = 0; amf < 2; ++amf)
            za[amf] = *(const bf16x8*)&YsZ[(wm * 64 + amf * 32 + l31) * (CIN + 4) + kq * 16 + lg2 * 8];
        #pragma unroll
        for (int cnf = 0; cnf < COUT / 64; ++cnf) {
            const int cblk = wn * (COUT / 64) + cnf;
            bf16x8 wf = *(const bf16x8*)(Wp + ((size_t)(kq * (COUT / 32) + cblk) * 64 + lane) * 8);
            #pragma unroll
            for (int amf = 0; amf < 2; ++amf)
                acc2[amf][cnf] = __builtin_amdgcn_mfma_f32_32x32x16_bf16(za[amf], wf, acc2[amf][cnf], 0, 0, 0);
        }
    }

    // ---- final write ----
    #pragma unroll
    for (int amf = 0; amf < 2; ++amf) {
        #pragma unroll
        for (int cnf = 0; cnf < COUT / 64; ++cnf) {
            const int col = wn * (COUT / 2) + cnf * 32 + l31;
            const float bb = bias[col];
            #pragma unroll
            for (int reg = 0; reg < 16; ++reg) {
                const int row = wm * 64 + amf * 32 + (reg & 3) + 8 * (reg >> 2) + 4 * lg2;
                const float di = sdinv[row];
                float h = di * acc2[amf][cnf][reg] + bb;
                if (RELU) h = fmaxf(h, 0.f);
                if (F32OUT) {
                    ((float*)outp)[((size_t)(b * NPTS + row0 + row)) * COUT + col] = h;
                } else {
                    const int j = row0 + row;
                    const int kt1 = j >> 6, ks1 = (j >> 4) & 3, kh1 = (j >> 3) & 1, e1 = j & 7;
                    size_t off = ((((size_t)(b * 32 + kt1) * (COUT / 32) + (col >> 5)) * 4 + ks1) * 512)
                                 + (size_t)((kh1 << 5) | (col & 31)) * 8 + e1;
                    ((unsigned short*)outp)[off] = f2b(di * h);
                }
            }
        }
    }
}

extern "C" void kernel_launch(void* const* d_in, const int* in_sizes, int n_in,
                              void* d_out, int out_size, void* d_ws, size_t ws_size,
                              hipStream_t stream) {
    const float* pts = (const float*)d_in[0];
    const float* W1  = (const float*)d_in[1];
    const float* b1  = (const float*)d_in[2];
    const float* W2  = (const float*)d_in[3];
    const float* b2  = (const float*)d_in[4];
    const float* W3  = (const float*)d_in[5];
    const float* b3  = (const float*)d_in[6];

    char* ws = (char*)d_ws;
    float*          dinv  = (float*)(ws + OFF_DINV);
    uint32_t*       maskT = (uint32_t*)(ws + OFF_MASK);
    unsigned short* G1    = (unsigned short*)(ws + OFF_G1);
    unsigned short* G2    = (unsigned short*)(ws + OFF_G2);
    unsigned short* Wp2   = (unsigned short*)(ws + OFF_WB);
    unsigned short* Wp3   = Wp2 + 64 * 128;
    float* out = (float*)d_out;

    k_cvtW2<<<dim3(128), dim3(256), 0, stream>>>(W2, W3, Wp2, Wp3);
    k_mask<<<dim3(NPTS / MROWS, BATCH), dim3(256), 0, stream>>>(pts, dinv, maskT);
    k_l1m<<<dim3(512), dim3(256), 0, stream>>>(pts, W1, b1, dinv, maskT, G1);
    // layer 2: Z=(A+I)@G1 (64 cols), H2=relu(dinv*Z@W2+b2), G2=dinv*H2 fragnat(128)
    k_gcnF<64, 128, true, false><<<dim3(512), dim3(256), 0, stream>>>(maskT, dinv, G1, Wp2, b2, G2);
    // layer 3: Z=(A+I)@G2 (128 cols), out = dinv*Z@W3 + b3 (fp32)
    k_gcnF<128, 256, false, true><<<dim3(512), dim3(256), 0, stream>>>(maskT, dinv, G2, Wp3, b3, out);
}

// Round 24
// 128.292 us; speedup vs baseline: 1.0783x; 1.0783x over previous
//
#include <hip/hip_runtime.h>
#include <hip/hip_bf16.h>
#include <cstdint>
#include <cstddef>

#define BATCH 32
#define NPTS  2048
#define NFLAT (BATCH * NPTS)   // 65536
#define MROWS 32               // rows per block in k_mask (8 per wave)

typedef __attribute__((ext_vector_type(8))) short bf16x8;    // 8 bf16 (4 VGPRs)
typedef __attribute__((ext_vector_type(4))) short bf16x4;    // 4 bf16 (2 VGPRs)
typedef __attribute__((ext_vector_type(4))) float f32x4;     // 16x16 C/D frag
typedef __attribute__((ext_vector_type(16))) float f32x16;   // 32x32 C/D frag

__device__ inline unsigned short f2b(float v) {
    __hip_bfloat16 h = __float2bfloat16(v);
    return __builtin_bit_cast(unsigned short, h);
}

__device__ inline void gl_lds16(const void* g, void* l) {
    __builtin_amdgcn_global_load_lds(
        (const __attribute__((address_space(1))) unsigned int*)g,
        (__attribute__((address_space(3))) unsigned int*)l, 16, 0, 0);
}

// ---------------- ws layout (bytes) ----------------
// dinv  : f32  [65536]            @ 0
// maskT : u32  [b][64][2048]      @ 262144    (16 MB)  TRANSPOSED: word-plane major
// G1    : bf16 fragnat(64)        @ 17039360  (8 MB)   dinv*h1, B-frag layout
// G2    : bf16 fragnat(128)       @ 50593792  (16 MB)  dinv*h2, B-frag layout
// Wp    : bf16 fragnat W2|W3      @ 67371008  (80 KB)
#define OFF_DINV 0
#define OFF_MASK 262144
#define OFF_G1   17039360
#define OFF_G2   50593792
#define OFF_WB   67371008

// ---------------- pack W2/W3 to bf16 fragment-native B-operand layout ----------------
__global__ __launch_bounds__(256) void k_cvtW2(const float* __restrict__ W2,
                                               const float* __restrict__ W3,
                                               unsigned short* __restrict__ Wp2,
                                               unsigned short* __restrict__ Wp3) {
    int i = blockIdx.x * 256 + threadIdx.x;   // grid 128 blocks -> i < 32768
    if (i < 64 * 128) {
        int k = i >> 7, c = i & 127;
        size_t off = (((size_t)(k >> 4) * 4 + (c >> 5)) * 64
                      + ((((k >> 3) & 1) << 5) | (c & 31))) * 8 + (k & 7);
        Wp2[off] = f2b(W2[i]);
    }
    {
        int k = i >> 8, c = i & 255;
        size_t off = (((size_t)(k >> 4) * 8 + (c >> 5)) * 64
                      + ((((k >> 3) & 1) << 5) | (c & 31))) * 8 + (k & 7);
        Wp3[off] = f2b(W3[i]);
    }
}

// ---------------- adjacency bitmask (transposed layout) + dinv ----------------
__global__ __launch_bounds__(256) void k_mask(const float* __restrict__ pts,
                                              float* __restrict__ dinv,
                                              uint32_t* __restrict__ maskT) {
    const int b = blockIdx.y;
    const int row0 = blockIdx.x * MROWS;
    const int tid = threadIdx.x, lane = tid & 63, wv = tid >> 6;
    __shared__ float px[2112], py[2112];
    __shared__ uint32_t tb[64][MROWS + 1];
    const float2* P = (const float2*)(pts + (size_t)b * NPTS * 2);
    for (int j = tid; j < NPTS; j += 256) {
        float2 p = P[j];
        px[j + (j >> 5)] = p.x; py[j + (j >> 5)] = p.y;
    }
    __syncthreads();
    const int base = 33 * lane;
    for (int rr = 0; rr < MROWS / 4; ++rr) {
        const int il = wv * (MROWS / 4) + rr;
        const int i = row0 + il;
        const float xi = px[i + (i >> 5)], yi = py[i + (i >> 5)];
        uint32_t bits = 0;
        #pragma unroll
        for (int t = 0; t < 32; ++t) {
            float dx = xi - px[base + t], dy = yi - py[base + t];
            bits |= (dx * dx + dy * dy < 1.0f) ? (1u << t) : 0u;
        }
        tb[lane][il] = bits;
        int cnt = __popc(bits);
        #pragma unroll
        for (int off = 32; off; off >>= 1) cnt += __shfl_xor(cnt, off);
        if (lane == 0) dinv[b * NPTS + i] = rsqrtf((float)(cnt + 1));
    }
    __syncthreads();
    const int w = tid >> 2, il0 = (tid & 3) * 8;
    uint32_t* dst = maskT + ((size_t)b * 64 + w) * NPTS + row0 + il0;
    #pragma unroll
    for (int e = 0; e < 8; ++e) dst[e] = tb[w][il0 + e];
}

// ---------------- layer 1 masked MFMA -> G1 = dinv*h1, fragment-native(64) ----------
__global__ __launch_bounds__(256) void k_l1m(const float* __restrict__ pts,
                                             const float* __restrict__ W1,
                                             const float* __restrict__ b1,
                                             const float* __restrict__ dinv,
                                             const uint32_t* __restrict__ maskT,
                                             unsigned short* __restrict__ G1) {
    const int lid = blockIdx.x;
    const int g = (lid & 7) * 64 + (lid >> 3);   // bijective XCD swizzle
    const int b = g >> 4;
    const int row0 = (g & 15) * 128;
    const int tid = threadIdx.x;
    const int lane = tid & 63, wv = tid >> 6;
    const int l15 = lane & 15, lg = lane >> 4;

    __shared__ uint32_t Ms[64][128];
    __shared__ unsigned short Ubf[NPTS], Vbf[NPTS];
    __shared__ alignas(128) unsigned short LUT4[64];
    __shared__ float sdinv[128];

    if (tid < 16) {
        ushort4 e;
        e.x = (tid & 1) ? 0x3F80 : 0; e.y = (tid & 2) ? 0x3F80 : 0;
        e.z = (tid & 4) ? 0x3F80 : 0; e.w = (tid & 8) ? 0x3F80 : 0;
        *(ushort4*)&LUT4[tid * 4] = e;
    }
    if (tid < 128) sdinv[tid] = dinv[b * NPTS + row0 + tid];
    {
        const float2* P = (const float2*)(pts + (size_t)b * NPTS * 2);
        const float* dvp = dinv + (size_t)b * NPTS;
        const int j0 = tid * 8;
        #pragma unroll
        for (int e = 0; e < 8; ++e) {
            float d = dvp[j0 + e]; float2 p = P[j0 + e];
            Ubf[j0 + e] = f2b(d * p.x); Vbf[j0 + e] = f2b(d * p.y);
        }
    }
    {
        const uint32_t* msrc = maskT + (size_t)b * 64 * NPTS + row0;
        #pragma unroll
        for (int k = 0; k < 8; ++k) {
            int idx = tid + k * 256;
            int w = idx >> 5, c4 = idx & 31;
            *(uint4*)&Ms[w][c4 * 4] = *(const uint4*)(msrc + (size_t)w * NPTS + c4 * 4);
        }
    }
    __syncthreads();

    f32x4 acc0 = (f32x4){0.f, 0.f, 0.f, 0.f};
    f32x4 acc1 = (f32x4){0.f, 0.f, 0.f, 0.f};
    const int lrow = wv * 32 + l15;
    const bf16x8 zb = (bf16x8){0, 0, 0, 0, 0, 0, 0, 0};

    for (int kt = 0; kt < 64; ++kt) {
        bf16x8 ub = *(const bf16x8*)&Ubf[kt * 32 + lg * 8];
        bf16x8 vb = *(const bf16x8*)&Vbf[kt * 32 + lg * 8];
        bf16x8 bf = (l15 == 0) ? ub : ((l15 == 1) ? vb : zb);
        #pragma unroll
        for (int mf = 0; mf < 2; ++mf) {
            const int row = row0 + lrow + mf * 16;
            uint32_t mw = Ms[kt][lrow + mf * 16];
            uint32_t by = (mw >> (lg * 8)) & 0xffu;
            bf16x4 lo = *(const bf16x4*)&LUT4[(by & 15u) * 4];
            bf16x4 hi = *(const bf16x4*)&LUT4[(by >> 4) * 4];
            bf16x8 af = __builtin_shufflevector(lo, hi, 0, 1, 2, 3, 4, 5, 6, 7);
            if (kt == (row >> 5)) {
                int e = (row & 31) - lg * 8;
                #pragma unroll
                for (int e2 = 0; e2 < 8; ++e2)
                    if (e2 == e) af[e2] = (short)0x4000;
            }
            if (mf == 0) acc0 = __builtin_amdgcn_mfma_f32_16x16x32_bf16(af, bf, acc0, 0, 0, 0);
            else         acc1 = __builtin_amdgcn_mfma_f32_16x16x32_bf16(af, bf, acc1, 0, 0, 0);
        }
    }

    float w1x[4], w1y[4], bb4[4];
    #pragma unroll
    for (int g4 = 0; g4 < 4; ++g4) {
        w1x[g4] = W1[l15 + 16 * g4];
        w1y[g4] = W1[64 + l15 + 16 * g4];
        bb4[g4] = b1[l15 + 16 * g4];
    }
    #pragma unroll
    for (int mf = 0; mf < 2; ++mf) {
        const int ks1 = mf | ((wv & 1) << 1);
        const int kt1 = (row0 >> 6) + (wv >> 1);
        #pragma unroll
        for (int r = 0; r < 4; ++r) {
            float av = (mf == 0) ? acc0[r] : acc1[r];
            float sx = __shfl(av, (lane & 48));
            float sy = __shfl(av, (lane & 48) | 1);
            const int rloc = wv * 32 + mf * 16 + lg * 4 + r;
            const float di = sdinv[rloc];
            const int e1 = (lg * 4 + r) & 7;
            const int kh1 = lg >> 1;
            #pragma unroll
            for (int g4 = 0; g4 < 4; ++g4) {
                float h = fmaxf(di * (sx * w1x[g4] + sy * w1y[g4]) + bb4[g4], 0.f);
                size_t off = ((((size_t)(b * 32 + kt1) * 2 + (g4 >> 1)) * 4 + ks1) * 512)
                             + (size_t)((kh1 << 5) | (l15 + 16 * (g4 & 1))) * 8 + e1;
                G1[off] = f2b(di * h);
            }
        }
    }
}

// ---------------- fused masked GCN layer, counted-vmcnt 2-phase pipeline ----------------
// Z=(A+I)@G (CIN cols) with DOUBLE-BUFFERED fragment-native staging: stage(kt+1)
// overlaps body(kt); s_waitcnt vmcnt(CIN/32) never drains to 0 in steady state.
// No per-tile vmem besides the stage (masks pre-staged in LDS) -> exact counting.
// Epilogue: Z -> bf16 LDS (unions the Ys dbuf), small GEMM vs fragnat W, write out/G.
template<int CIN, int COUT, bool RELU, bool F32OUT>
__global__ __launch_bounds__(256, 2) void k_gcnF(const uint32_t* __restrict__ maskT,
                                                 const float* __restrict__ dinv,
                                                 const unsigned short* __restrict__ G,
                                                 const unsigned short* __restrict__ Wp,
                                                 const float* __restrict__ bias,
                                                 void* __restrict__ outp) {
    constexpr int BM = 128;
    constexpr int NF = CIN / 64;          // 32-col B-frags per wave (2x2 wave grid)
    constexpr int LSZ = (2 * CIN * 64 > 128 * (CIN + 4)) ? 2 * CIN * 64 : 128 * (CIN + 4);
    const int lid = blockIdx.x;
    const int g = (lid & 7) * 64 + (lid >> 3);   // bijective XCD swizzle
    const int b = g >> 4;
    const int row0 = (g & 15) * BM;
    const int tid = threadIdx.x;
    const int lane = tid & 63, wv = tid >> 6;
    const int wm = wv >> 1, wn = wv & 1;
    const int l31 = lane & 31, lg2 = lane >> 5;

    __shared__ alignas(16) unsigned short YsZ[LSZ];   // Ys dbuf (main) / Zs (epilogue)
    __shared__ uint32_t Ms[64][BM];
    __shared__ alignas(128) unsigned short LUT4[64];
    __shared__ float sdinv[BM];

    if (tid < 16) {
        ushort4 e;
        e.x = (tid & 1) ? 0x3F80 : 0; e.y = (tid & 2) ? 0x3F80 : 0;
        e.z = (tid & 4) ? 0x3F80 : 0; e.w = (tid & 8) ? 0x3F80 : 0;
        *(ushort4*)&LUT4[tid * 4] = e;
    }
    if (tid < BM) sdinv[tid] = dinv[b * NPTS + row0 + tid];
    {
        const uint32_t* msrc = maskT + (size_t)b * 64 * NPTS + row0;
        #pragma unroll
        for (int k = 0; k < 8; ++k) {
            int idx = tid + k * 256;
            int w = idx >> 5, c4 = idx & 31;
            *(uint4*)&Ms[w][c4 * 4] = *(const uint4*)(msrc + (size_t)w * NPTS + c4 * 4);
        }
    }

    f32x16 acc[2][NF];
    #pragma unroll
    for (int mf = 0; mf < 2; ++mf)
        #pragma unroll
        for (int nf = 0; nf < NF; ++nf)
            #pragma unroll
            for (int r = 0; r < 16; ++r)
                acc[mf][nf][r] = 0.f;

    const int ktd = (row0 >> 6) + wm;
    const int arow = wm * 64 + l31;

    auto stage = [&](int buf, int kt) {
        const unsigned short* ysrc = G + (size_t)(b * 32 + kt) * (CIN / 32) * 2048;
        #pragma unroll
        for (int q = 0; q < CIN / 32; ++q) {
            int fi = wv * (CIN / 32) + q;
            gl_lds16(ysrc + (size_t)fi * 512 + lane * 8,
                     (char*)YsZ + buf * (CIN * 128) + fi * 1024);
        }
    };
    auto body = [&](int buf, int kt) {
        const char* ybase = (const char*)YsZ + buf * (CIN * 128);
        uint32_t M[2][2];
        #pragma unroll
        for (int mf = 0; mf < 2; ++mf)
            #pragma unroll
            for (int q = 0; q < 2; ++q)
                M[mf][q] = Ms[kt * 2 + q][arow + mf * 32];
        #pragma unroll
        for (int ks = 0; ks < 4; ++ks) {
            bf16x8 af[2];
            #pragma unroll
            for (int mf = 0; mf < 2; ++mf) {
                uint32_t by = (M[mf][ks >> 1] >> (((ks & 1) * 2 + lg2) * 8)) & 0xffu;
                bf16x4 lo = *(const bf16x4*)&LUT4[(by & 15u) * 4];
                bf16x4 hi = *(const bf16x4*)&LUT4[(by >> 4) * 4];
                af[mf] = __builtin_shufflevector(lo, hi, 0, 1, 2, 3, 4, 5, 6, 7);
            }
            if (kt == ktd) {
                #pragma unroll
                for (int mf = 0; mf < 2; ++mf) {
                    int e = mf * 32 + l31 - ks * 16 - lg2 * 8;
                    #pragma unroll
                    for (int e2 = 0; e2 < 8; ++e2)
                        if (e2 == e) af[mf][e2] = (short)0x4000;
                }
            }
            #pragma unroll
            for (int nf = 0; nf < NF; ++nf) {
                bf16x8 bf = *(const bf16x8*)(ybase
                            + ((((wn * NF + nf) * 4 + ks) * 64 + lane) << 4));
                #pragma unroll
                for (int mf = 0; mf < 2; ++mf)
                    acc[mf][nf] = __builtin_amdgcn_mfma_f32_32x32x16_bf16(af[mf], bf, acc[mf][nf], 0, 0, 0);
            }
        }
    };

    __syncthreads();            // publish LUT/Ms/sdinv; vmem queue empty
    stage(0, 0);
    for (int kt = 0; kt < 32; kt += 2) {
        stage(1, kt + 1);
        if constexpr (CIN == 128) asm volatile("s_waitcnt vmcnt(4)" ::: "memory");
        else                      asm volatile("s_waitcnt vmcnt(2)" ::: "memory");
        __builtin_amdgcn_s_barrier();
        body(0, kt);
        __builtin_amdgcn_s_barrier();
        if (kt + 2 < 32) {
            stage(0, kt + 2);
            if constexpr (CIN == 128) asm volatile("s_waitcnt vmcnt(4)" ::: "memory");
            else                      asm volatile("s_waitcnt vmcnt(2)" ::: "memory");
        } else {
            asm volatile("s_waitcnt vmcnt(0)" ::: "memory");
        }
        __builtin_amdgcn_s_barrier();
        body(1, kt + 1);
        __builtin_amdgcn_s_barrier();
    }

    // ---- epilogue stage 1: Z -> bf16 LDS [128][CIN+4] (aliases Ys dbuf; drained) ----
    #pragma unroll
    for (int mf = 0; mf < 2; ++mf)
        #pragma unroll
        for (int nf = 0; nf < NF; ++nf) {
            const int col = wn * (CIN / 2) + nf * 32 + l31;
            #pragma unroll
            for (int reg = 0; reg < 16; ++reg) {
                const int row = wm * 64 + mf * 32 + (reg & 3) + 8 * (reg >> 2) + 4 * lg2;
                YsZ[row * (CIN + 4) + col] = f2b(acc[mf][nf][reg]);
            }
        }
    __syncthreads();

    // ---- epilogue stage 2: Z @ W (+bias), W fragment-native from global (L2-hot) ----
    f32x16 acc2[2][COUT / 64];
    #pragma unroll
    for (int amf = 0; amf < 2; ++amf)
        #pragma unroll
        for (int cnf = 0; cnf < COUT / 64; ++cnf)
            #pragma unroll
            for (int r = 0; r < 16; ++r)
                acc2[amf][cnf][r] = 0.f;

    #pragma unroll
    for (int kq = 0; kq < CIN / 16; ++kq) {
        bf16x8 za[2];
        #pragma unroll
        for (int amf = 0; amf < 2; ++amf)
            za[amf] = *(const bf16x8*)&YsZ[(wm * 64 + amf * 32 + l31) * (CIN + 4) + kq * 16 + lg2 * 8];
        #pragma unroll
        for (int cnf = 0; cnf < COUT / 64; ++cnf) {
            const int cblk = wn * (COUT / 64) + cnf;
            bf16x8 wf = *(const bf16x8*)(Wp + ((size_t)(kq * (COUT / 32) + cblk) * 64 + lane) * 8);
            #pragma unroll
            for (int amf = 0; amf < 2; ++amf)
                acc2[amf][cnf] = __builtin_amdgcn_mfma_f32_32x32x16_bf16(za[amf], wf, acc2[amf][cnf], 0, 0, 0);
        }
    }

    // ---- final write ----
    #pragma unroll
    for (int amf = 0; amf < 2; ++amf) {
        #pragma unroll
        for (int cnf = 0; cnf < COUT / 64; ++cnf) {
            const int col = wn * (COUT / 2) + cnf * 32 + l31;
            const float bb = bias[col];
            #pragma unroll
            for (int reg = 0; reg < 16; ++reg) {
                const int row = wm * 64 + amf * 32 + (reg & 3) + 8 * (reg >> 2) + 4 * lg2;
                const float di = sdinv[row];
                float h = di * acc2[amf][cnf][reg] + bb;
                if (RELU) h = fmaxf(h, 0.f);
                if (F32OUT) {
                    ((float*)outp)[((size_t)(b * NPTS + row0 + row)) * COUT + col] = h;
                } else {
                    const int j = row0 + row;
                    const int kt1 = j >> 6, ks1 = (j >> 4) & 3, kh1 = (j >> 3) & 1, e1 = j & 7;
                    size_t off = ((((size_t)(b * 32 + kt1) * (COUT / 32) + (col >> 5)) * 4 + ks1) * 512)
                                 + (size_t)((kh1 << 5) | (col & 31)) * 8 + e1;
                    ((unsigned short*)outp)[off] = f2b(di * h);
                }
            }
        }
    }
}

extern "C" void kernel_launch(void* const* d_in, const int* in_sizes, int n_in,
                              void* d_out, int out_size, void* d_ws, size_t ws_size,
                              hipStream_t stream) {
    const float* pts = (const float*)d_in[0];
    const float* W1  = (const float*)d_in[1];
    const float* b1  = (const float*)d_in[2];
    const float* W2  = (const float*)d_in[3];
    const float* b2  = (const float*)d_in[4];
    const float* W3  = (const float*)d_in[5];
    const float* b3  = (const float*)d_in[6];

    char* ws = (char*)d_ws;
    float*          dinv  = (float*)(ws + OFF_DINV);
    uint32_t*       maskT = (uint32_t*)(ws + OFF_MASK);
    unsigned short* G1    = (unsigned short*)(ws + OFF_G1);
    unsigned short* G2    = (unsigned short*)(ws + OFF_G2);
    unsigned short* Wp2   = (unsigned short*)(ws + OFF_WB);
    unsigned short* Wp3   = Wp2 + 64 * 128;
    float* out = (float*)d_out;

    k_cvtW2<<<dim3(128), dim3(256), 0, stream>>>(W2, W3, Wp2, Wp3);
    k_mask<<<dim3(NPTS / MROWS, BATCH), dim3(256), 0, stream>>>(pts, dinv, maskT);
    k_l1m<<<dim3(512), dim3(256), 0, stream>>>(pts, W1, b1, dinv, maskT, G1);
    // layer 2: Z=(A+I)@G1 (64 cols), H2=relu(dinv*Z@W2+b2), G2=dinv*H2 fragnat(128)
    k_gcnF<64, 128, true, false><<<dim3(512), dim3(256), 0, stream>>>(maskT, dinv, G1, Wp2, b2, G2);
    // layer 3: Z=(A+I)@G2 (128 cols), out = dinv*Z@W3 + b3 (fp32)
    k_gcnF<128, 256, false, true><<<dim3(512), dim3(256), 0, stream>>>(maskT, dinv, G2, Wp3, b3, out);
}